// Round 5
// baseline (987.332 us; speedup 1.0000x reference)
//
#include <hip/hip_runtime.h>

#define NB 256
#define NT 1024
#define NC 128
#define ND 64

typedef _Float16 f16x2_t __attribute__((ext_vector_type(2)));

__device__ __forceinline__ float fexp2(float x){
#if __has_builtin(__builtin_amdgcn_exp2f)
  return __builtin_amdgcn_exp2f(x);
#else
  return exp2f(x);
#endif
}
__device__ __forceinline__ float frcp_(float x){
#if __has_builtin(__builtin_amdgcn_rcpf)
  return __builtin_amdgcn_rcpf(x);
#else
  return 1.0f / x;
#endif
}
__device__ __forceinline__ float sigmoid_f(float x){
  return frcp_(1.0f + fexp2(-1.4426950408889634f * x));
}
__device__ __forceinline__ float tanh_f(float x){
  return 1.0f - 2.0f * frcp_(fexp2(2.8853900817779268f * x) + 1.0f);
}
// exp(CLAMP*0.636*atan(s/CLAMP)) with CLAMP=5 -> exp(3.18*atan(0.2*s))
__device__ __forceinline__ float e_func(float s){
  float u = 0.2f * s;
  float au = fabsf(u);
  bool inv = au > 1.0f;
  float v = inv ? frcp_(au) : au;
  float v2 = v * v;
  float pp = -0.0117212f;
  pp = pp * v2 + 0.05265332f;
  pp = pp * v2 - 0.11643287f;
  pp = pp * v2 + 0.19354346f;
  pp = pp * v2 - 0.33262347f;
  pp = pp * v2 + 0.99997726f;
  float at = pp * v;
  if (inv) at = 1.5707963267948966f - at;
  at = __builtin_copysignf(at, u);
  return fexp2(4.5877702301963f * at); // 3.18 * log2(e) * atan
}

__device__ __forceinline__ unsigned packh(float a, float b){
  union { _Float16 h[2]; unsigned u; } v;
  v.h[0] = (_Float16)a; v.h[1] = (_Float16)b;
  return v.u;
}
__device__ __forceinline__ float fdot2u(unsigned a, unsigned b, float c){
#if __has_builtin(__builtin_amdgcn_fdot2)
  return __builtin_amdgcn_fdot2(__builtin_bit_cast(f16x2_t, a), __builtin_bit_cast(f16x2_t, b), c, false);
#else
  f16x2_t av = __builtin_bit_cast(f16x2_t, a);
  f16x2_t bv = __builtin_bit_cast(f16x2_t, b);
  return c + (float)av[0]*(float)bv[0] + (float)av[1]*(float)bv[1];
#endif
}

// read 32 packed-f16 dwords from a 128B LDS slot via 8 uniform (broadcast) b128 reads
__device__ __forceinline__ void load_packs(unsigned* hv, const unsigned* slot){
  const uint4* q = reinterpret_cast<const uint4*>(slot);
  #pragma unroll
  for (int j = 0; j < 8; ++j){
    uint4 v = q[j];
    hv[4*j+0] = v.x; hv[4*j+1] = v.y; hv[4*j+2] = v.z; hv[4*j+3] = v.w;
  }
}

// Wave-decoupled pipeline, no barriers in the main loop.
// Waves: 0=A1 (gh2+act2), 1=C1 (gh1+act1), 2=A2 (gx2), 3=C2 (gy1),
//        4=D (Wo1+y2), 5=B (Wo2+y1)
// SIMD pairing (w%4): S0={A1,D}, S1={C1,B}, S2={A2}, S3={C2}
__global__ __launch_bounds__(384, 1)
void glow_gru_kernel(const float* __restrict__ x,
                     const float* __restrict__ Wx1, const float* __restrict__ Wh1,
                     const float* __restrict__ bx1, const float* __restrict__ bh1,
                     const float* __restrict__ Wo1, const float* __restrict__ bo1,
                     const float* __restrict__ Wx2, const float* __restrict__ Wh2,
                     const float* __restrict__ bx2, const float* __restrict__ bh2,
                     const float* __restrict__ Wo2, const float* __restrict__ bo2,
                     float* __restrict__ out)
{
  __shared__ int seqv[8];                              // per-wave progress counters
  __shared__ __align__(16) unsigned h2p[8][32];        // h2 f16 packs ring (A1 -> B, self)
  __shared__ __align__(16) unsigned h1p[8][32];        // h1 packs ring (C1 -> D, self)
  __shared__ __align__(16) unsigned y1p[8][32];        // y1 packs ring (B -> C2)
  __shared__ __align__(16) unsigned x2s[2][32];        // A2 private x2 pack scratch
  __shared__ float p2x[8][192];                        // gx2 partials ring (A2 -> A1)
  __shared__ float p1x[8][192];                        // gy1 partials ring (C2 -> C1)

  const int l = threadIdx.x;
  const int w = l >> 6;
  const int i = l & 63;
  const int b = blockIdx.x;
  const long xbase = (long)b * NT * NC;

  if (l < 8) seqv[l] = -1;
  if (l < 32){ h2p[7][l] = 0u; h1p[7][l] = 0u; }
  __syncthreads();

  volatile int* seq = seqv;

  if (w <= 1){
    // ================= R: recurrent gates (gh) + activation =================
    const float* WH = (w == 0) ? Wh2 : Wh1;
    const float* bx = (w == 0) ? bx2 : bx1;
    const float* bh = (w == 0) ? bh2 : bh1;
    unsigned (*hr)[32]  = (w == 0) ? h2p : h1p;
    float    (*pr)[192] = (w == 0) ? p2x : p1x;
    const int srcw  = (w == 0) ? 2 : 3;   // A2 / C2 produce x-side partials
    const int consw = (w == 0) ? 5 : 4;   // B / D consume our h ring

    unsigned wr[32], wz[32], wn[32];
    #pragma unroll
    for (int k2 = 0; k2 < 32; ++k2){
      wr[k2] = packh(WH[(2*k2)*192 + i],       WH[(2*k2+1)*192 + i]);
      wz[k2] = packh(WH[(2*k2)*192 + 64 + i],  WH[(2*k2+1)*192 + 64 + i]);
      wn[k2] = packh(WH[(2*k2)*192 + 128 + i], WH[(2*k2+1)*192 + 128 + i]);
    }
    const float bR = bx[i] + bh[i];
    const float bZ = bx[64+i] + bh[64+i];
    const float bNX = bx[128+i], bNH = bh[128+i];
    float h = 0.f;

    for (int n = 0; n < NT; ++n){
      int v0 = seq[srcw];                 // early poll (overlaps dots)
      unsigned hv[32];
      load_packs(hv, hr[(n-1) & 7]);
      float rh = 0.f, zh = 0.f, nh = 0.f;
      #pragma unroll
      for (int k2 = 0; k2 < 32; ++k2){
        unsigned hk = hv[k2];
        rh = fdot2u(hk, wr[k2], rh);
        zh = fdot2u(hk, wz[k2], zh);
        nh = fdot2u(hk, wn[k2], nh);
      }
      while (v0 < n) { v0 = seq[srcw]; }
      asm volatile("" ::: "memory");
      float rx = pr[n & 7][i], zx = pr[n & 7][64 + i], nx = pr[n & 7][128 + i];
      float r = sigmoid_f(rx + rh + bR);
      float z = sigmoid_f(zx + zh + bZ);
      float nn2 = tanh_f(nx + bNX + r*(nh + bNH));
      h = (1.f - z)*nn2 + z*h;
      while (seq[consw] < n - 8) {}
      asm volatile("" ::: "memory");
      reinterpret_cast<_Float16*>(hr[n & 7])[i] = (_Float16)h;
      asm volatile("s_waitcnt lgkmcnt(0)" ::: "memory");
      if (i == 0) seq[w] = n;
    }
  } else if (w <= 3){
    // ================= X: feed-forward gates (gx2 / gy1) =================
    const float* WXm = (w == 2) ? Wx2 : Wx1;
    float (*pr)[192] = (w == 2) ? p2x : p1x;
    const int consw = (w == 2) ? 0 : 1;   // A1 / C1 consume our partials

    unsigned wr[32], wz[32], wn[32];
    #pragma unroll
    for (int k2 = 0; k2 < 32; ++k2){
      wr[k2] = packh(WXm[(2*k2)*192 + i],       WXm[(2*k2+1)*192 + i]);
      wz[k2] = packh(WXm[(2*k2)*192 + 64 + i],  WXm[(2*k2+1)*192 + 64 + i]);
      wn[k2] = packh(WXm[(2*k2)*192 + 128 + i], WXm[(2*k2+1)*192 + 128 + i]);
    }
    float xr0 = 0.f, xr1 = 0.f;
    if (w == 2){
      xr0 = x[xbase + 64 + i];
      xr1 = x[xbase + NC + 64 + i];
    }

    for (int n = 0; n < NT; ++n){
      unsigned hv[32];
      if (w == 2){
        reinterpret_cast<_Float16*>(x2s[n & 1])[i] = (_Float16)xr0;
        xr0 = xr1;
        int nn = (n + 2 < NT) ? n + 2 : NT - 1;
        xr1 = x[xbase + (long)nn*NC + 64 + i];
        load_packs(hv, x2s[n & 1]);      // compiler orders same-array LDS w->r
      } else {
        while (seq[5] < n) {}
        asm volatile("" ::: "memory");
        load_packs(hv, y1p[n & 7]);
      }
      float rx = 0.f, zx = 0.f, nx = 0.f;
      #pragma unroll
      for (int k2 = 0; k2 < 32; ++k2){
        unsigned hk = hv[k2];
        rx = fdot2u(hk, wr[k2], rx);
        zx = fdot2u(hk, wz[k2], zx);
        nx = fdot2u(hk, wn[k2], nx);
      }
      while (seq[consw] < n - 8) {}
      asm volatile("" ::: "memory");
      pr[n & 7][i] = rx; pr[n & 7][64 + i] = zx; pr[n & 7][128 + i] = nx;
      asm volatile("s_waitcnt lgkmcnt(0)" ::: "memory");
      if (i == 0) seq[w] = n;
    }
  } else {
    // ================= H: output head (Wo + y) =================
    const float* WOm = (w == 5) ? Wo2 : Wo1;
    const float* bo  = (w == 5) ? bo2 : bo1;
    unsigned (*hr)[32] = (w == 5) ? h2p : h1p;
    const int srcw = (w == 5) ? 0 : 1;    // A1 / C1 produce h
    const int xoff = (w == 5) ? 0 : 64;   // y1 uses x1, y2 uses x2

    unsigned wsd[32], wtd[32];
    #pragma unroll
    for (int k2 = 0; k2 < 32; ++k2){
      wsd[k2] = packh(WOm[(2*k2)*128 + i],      WOm[(2*k2+1)*128 + i]);
      wtd[k2] = packh(WOm[(2*k2)*128 + 64 + i], WOm[(2*k2+1)*128 + 64 + i]);
    }
    const float bS = bo[i], bT = bo[64+i];
    float xr0 = x[xbase + xoff + i];
    float xr1 = x[xbase + NC + xoff + i];

    for (int n = 0; n < NT; ++n){
      while (seq[srcw] < n) {}
      asm volatile("" ::: "memory");
      unsigned hv[32];
      load_packs(hv, hr[n & 7]);
      float s = 0.f, t = 0.f;
      #pragma unroll
      for (int k2 = 0; k2 < 32; ++k2){
        unsigned hk = hv[k2];
        s = fdot2u(hk, wsd[k2], s);
        t = fdot2u(hk, wtd[k2], t);
      }
      float y = e_func(s + bS) * xr0 + (t + bT);
      out[xbase + (long)n*NC + xoff + i] = y;
      if (w == 5){
        while (seq[3] < n - 8) {}
        asm volatile("" ::: "memory");
        reinterpret_cast<_Float16*>(y1p[n & 7])[i] = (_Float16)y;
      }
      xr0 = xr1;
      int nn = (n + 2 < NT) ? n + 2 : NT - 1;
      xr1 = x[xbase + (long)nn*NC + xoff + i];
      asm volatile("s_waitcnt lgkmcnt(0)" ::: "memory");
      if (i == 0) seq[w] = n;
    }
  }
}

extern "C" void kernel_launch(void* const* d_in, const int* in_sizes, int n_in,
                              void* d_out, int out_size, void* d_ws, size_t ws_size,
                              hipStream_t stream) {
  const float* x   = (const float*)d_in[0];
  const float* Wx1 = (const float*)d_in[1];
  const float* Wh1 = (const float*)d_in[2];
  const float* bx1 = (const float*)d_in[3];
  const float* bh1 = (const float*)d_in[4];
  const float* Wo1 = (const float*)d_in[5];
  const float* bo1 = (const float*)d_in[6];
  const float* Wx2 = (const float*)d_in[7];
  const float* Wh2 = (const float*)d_in[8];
  const float* bx2 = (const float*)d_in[9];
  const float* bh2 = (const float*)d_in[10];
  const float* Wo2 = (const float*)d_in[11];
  const float* bo2 = (const float*)d_in[12];
  float* out = (float*)d_out;

  hipLaunchKernelGGL(glow_gru_kernel, dim3(NB), dim3(384), 0, stream,
                     x, Wx1, Wh1, bx1, bh1, Wo1, bo1,
                     Wx2, Wh2, bx2, bh2, Wo2, bo2, out);
}

// Round 6
// 747.071 us; speedup vs baseline: 1.3216x; 1.3216x over previous
//
#include <hip/hip_runtime.h>

#define NB 256
#define NT 1024
#define NC 128
#define ND 64

typedef _Float16 f16x2_t __attribute__((ext_vector_type(2)));

__device__ __forceinline__ float fexp2(float x){
#if __has_builtin(__builtin_amdgcn_exp2f)
  return __builtin_amdgcn_exp2f(x);
#else
  return exp2f(x);
#endif
}
__device__ __forceinline__ float frcp_(float x){
#if __has_builtin(__builtin_amdgcn_rcpf)
  return __builtin_amdgcn_rcpf(x);
#else
  return 1.0f / x;
#endif
}
__device__ __forceinline__ float sigmoid_f(float x){
  return frcp_(1.0f + fexp2(-1.4426950408889634f * x));
}
__device__ __forceinline__ float tanh_f(float x){
  return 1.0f - 2.0f * frcp_(fexp2(2.8853900817779268f * x) + 1.0f);
}
// exp(CLAMP*0.636*atan(s/CLAMP)) with CLAMP=5 -> exp(3.18*atan(0.2*s))
__device__ __forceinline__ float e_func(float s){
  float u = 0.2f * s;
  float au = fabsf(u);
  bool inv = au > 1.0f;
  float v = inv ? frcp_(au) : au;
  float v2 = v * v;
  float pp = -0.0117212f;
  pp = pp * v2 + 0.05265332f;
  pp = pp * v2 - 0.11643287f;
  pp = pp * v2 + 0.19354346f;
  pp = pp * v2 - 0.33262347f;
  pp = pp * v2 + 0.99997726f;
  float at = pp * v;
  if (inv) at = 1.5707963267948966f - at;
  at = __builtin_copysignf(at, u);
  return fexp2(4.5877702301963f * at); // 3.18 * log2(e) * atan
}

__device__ __forceinline__ unsigned packh(float a, float b){
  union { _Float16 h[2]; unsigned u; } v;
  v.h[0] = (_Float16)a; v.h[1] = (_Float16)b;
  return v.u;
}
__device__ __forceinline__ float fdot2u(unsigned a, unsigned b, float c){
#if __has_builtin(__builtin_amdgcn_fdot2)
  return __builtin_amdgcn_fdot2(__builtin_bit_cast(f16x2_t, a), __builtin_bit_cast(f16x2_t, b), c, false);
#else
  f16x2_t av = __builtin_bit_cast(f16x2_t, a);
  f16x2_t bv = __builtin_bit_cast(f16x2_t, b);
  return c + (float)av[0]*(float)bv[0] + (float)av[1]*(float)bv[1];
#endif
}

// read 32 packed-f16 dwords from a 128B LDS slot via 8 uniform (broadcast) b128 reads
__device__ __forceinline__ void load_packs(unsigned* hv, const unsigned* slot){
  const uint4* q = reinterpret_cast<const uint4*>(slot);
  #pragma unroll
  for (int j = 0; j < 8; ++j){
    uint4 v = q[j];
    hv[4*j+0] = v.x; hv[4*j+1] = v.y; hv[4*j+2] = v.z; hv[4*j+3] = v.w;
  }
}

// LDS-only barrier in ONE asm blob: orders LDS, lets global loads/stores fly.
// No sched_barrier pins (R4 lesson), no per-site setprio.
#define BAR() asm volatile("s_waitcnt lgkmcnt(0)\n\ts_barrier" ::: "memory")

// 6-wave pipelined, ONE barrier per step.
// Wave order (SIMD = w%4): w0=A2(gx2)@j   w1=C2(gy1)@j-3   w2=A1(h2)@j-1
//                          w3=C1(h1)@j-4  w4=B(Wo2+y1)@j-2 w5=D(Wo1+y2)@j-5
// SIMDs: S0={A2,B} S1={C2,D} S2={A1} S3={C1}
__global__ __launch_bounds__(384, 1)
void glow_gru_kernel(const float* __restrict__ x,
                     const float* __restrict__ Wx1, const float* __restrict__ Wh1,
                     const float* __restrict__ bx1, const float* __restrict__ bh1,
                     const float* __restrict__ Wo1, const float* __restrict__ bo1,
                     const float* __restrict__ Wx2, const float* __restrict__ Wh2,
                     const float* __restrict__ bx2, const float* __restrict__ bh2,
                     const float* __restrict__ Wo2, const float* __restrict__ bo2,
                     float* __restrict__ out)
{
  __shared__ __align__(16) unsigned h2p[4][32];   // h2(n) packs, slot n&3   (A1 -> A1,B)
  __shared__ __align__(16) unsigned h1p[4][32];   // h1(p) packs, slot p&3   (C1 -> C1,D)
  __shared__ __align__(16) unsigned y1p[4][32];   // y1(m) packs, slot m&3   (B -> C2)
  __shared__ __align__(16) unsigned x2p[2][32];   // x2(n) packs, slot n&1   (A2 -> A2, staged 1 ahead)
  __shared__ float px2[4][192];                   // gx2(n) partials, slot n&3 (A2 -> A1)
  __shared__ float py1[4][192];                   // gy1(m') partials, slot m'&3 (C2 -> C1)

  const int l = threadIdx.x;
  const int w = l >> 6;
  const int i = l & 63;
  const int b = blockIdx.x;
  const long xbase = (long)b * NT * NC;

  if (l < 32){ h2p[3][l] = 0u; h1p[3][l] = 0u; }

  // role-dependent register state
  unsigned wa[32], wb[32], wc[32];
  float b0 = 0.f, b1 = 0.f, b2 = 0.f, b3 = 0.f;
  float xr0 = 0.f, xr1 = 0.f;
  float h = 0.f;

  if (w == 0){            // A2: gx2, operand x2, matrix Wx2
    #pragma unroll
    for (int k2 = 0; k2 < 32; ++k2){
      wa[k2] = packh(Wx2[(2*k2)*192 + i],       Wx2[(2*k2+1)*192 + i]);
      wb[k2] = packh(Wx2[(2*k2)*192 + 64 + i],  Wx2[(2*k2+1)*192 + 64 + i]);
      wc[k2] = packh(Wx2[(2*k2)*192 + 128 + i], Wx2[(2*k2+1)*192 + 128 + i]);
    }
    float x0v = x[xbase + 64 + i];                       // x2(0)
    reinterpret_cast<_Float16*>(x2p[0])[i] = (_Float16)x0v;
    xr0 = x[xbase + (long)NC + 64 + i];                  // x2(1)
    xr1 = x[xbase + 2L*NC + 64 + i];                     // x2(2)
  } else if (w == 1){     // C2: gy1, operand y1, matrix Wx1
    #pragma unroll
    for (int k2 = 0; k2 < 32; ++k2){
      wa[k2] = packh(Wx1[(2*k2)*192 + i],       Wx1[(2*k2+1)*192 + i]);
      wb[k2] = packh(Wx1[(2*k2)*192 + 64 + i],  Wx1[(2*k2+1)*192 + 64 + i]);
      wc[k2] = packh(Wx1[(2*k2)*192 + 128 + i], Wx1[(2*k2+1)*192 + 128 + i]);
    }
  } else if (w == 2){     // A1: h2 recurrence, matrix Wh2
    #pragma unroll
    for (int k2 = 0; k2 < 32; ++k2){
      wa[k2] = packh(Wh2[(2*k2)*192 + i],       Wh2[(2*k2+1)*192 + i]);
      wb[k2] = packh(Wh2[(2*k2)*192 + 64 + i],  Wh2[(2*k2+1)*192 + 64 + i]);
      wc[k2] = packh(Wh2[(2*k2)*192 + 128 + i], Wh2[(2*k2+1)*192 + 128 + i]);
    }
    b0 = bx2[i] + bh2[i];
    b1 = bx2[64+i] + bh2[64+i];
    b2 = bx2[128+i];        // bNX
    b3 = bh2[128+i];        // bNH
  } else if (w == 3){     // C1: h1 recurrence, matrix Wh1
    #pragma unroll
    for (int k2 = 0; k2 < 32; ++k2){
      wa[k2] = packh(Wh1[(2*k2)*192 + i],       Wh1[(2*k2+1)*192 + i]);
      wb[k2] = packh(Wh1[(2*k2)*192 + 64 + i],  Wh1[(2*k2+1)*192 + 64 + i]);
      wc[k2] = packh(Wh1[(2*k2)*192 + 128 + i], Wh1[(2*k2+1)*192 + 128 + i]);
    }
    b0 = bx1[i] + bh1[i];
    b1 = bx1[64+i] + bh1[64+i];
    b2 = bx1[128+i];
    b3 = bh1[128+i];
  } else if (w == 4){     // B: Wo2 head -> y1
    #pragma unroll
    for (int k2 = 0; k2 < 32; ++k2){
      wa[k2] = packh(Wo2[(2*k2)*128 + i],      Wo2[(2*k2+1)*128 + i]);
      wb[k2] = packh(Wo2[(2*k2)*128 + 64 + i], Wo2[(2*k2+1)*128 + 64 + i]);
    }
    b0 = bo2[i]; b1 = bo2[64+i];
    xr0 = x[xbase + i];                                  // x1(0)
    xr1 = x[xbase + (long)NC + i];                       // x1(1)
  } else {                // D: Wo1 head -> y2
    #pragma unroll
    for (int k2 = 0; k2 < 32; ++k2){
      wa[k2] = packh(Wo1[(2*k2)*128 + i],      Wo1[(2*k2+1)*128 + i]);
      wb[k2] = packh(Wo1[(2*k2)*128 + 64 + i], Wo1[(2*k2+1)*128 + 64 + i]);
    }
    b0 = bo1[i]; b1 = bo1[64+i];
    xr0 = x[xbase + 64 + i];                             // x2(0)
    xr1 = x[xbase + (long)NC + 64 + i];                  // x2(1)
  }
  __syncthreads();

  if (w == 0){
    // ===== A2: px2(n) from staged x2 pack; stage x2(n+1) =====
    for (int j = 0; j <= NT + 4; ++j){
      const int n = j;
      if (n < NT){
        unsigned hv[32];
        load_packs(hv, x2p[n & 1]);
        float a0 = 0.f, a1 = 0.f, a2 = 0.f;
        #pragma unroll
        for (int k2 = 0; k2 < 32; ++k2){
          unsigned hk = hv[k2];
          a0 = fdot2u(hk, wa[k2], a0);
          a1 = fdot2u(hk, wb[k2], a1);
          a2 = fdot2u(hk, wc[k2], a2);
        }
        px2[n & 3][i]       = a0;
        px2[n & 3][64 + i]  = a1;
        px2[n & 3][128 + i] = a2;
        if (n + 1 < NT){
          reinterpret_cast<_Float16*>(x2p[(n+1) & 1])[i] = (_Float16)xr0;
          xr0 = xr1;
          const int nn = (n + 3 < NT) ? n + 3 : NT - 1;
          xr1 = x[xbase + (long)nn*NC + 64 + i];
        }
      }
      BAR();
    }
  } else if (w == 1){
    // ===== C2: py1(m') from y1 packs =====
    for (int j = 0; j <= NT + 4; ++j){
      const int m = j - 3;
      if (m >= 0 && m < NT){
        unsigned hv[32];
        load_packs(hv, y1p[m & 3]);
        float a0 = 0.f, a1 = 0.f, a2 = 0.f;
        #pragma unroll
        for (int k2 = 0; k2 < 32; ++k2){
          unsigned hk = hv[k2];
          a0 = fdot2u(hk, wa[k2], a0);
          a1 = fdot2u(hk, wb[k2], a1);
          a2 = fdot2u(hk, wc[k2], a2);
        }
        py1[m & 3][i]       = a0;
        py1[m & 3][64 + i]  = a1;
        py1[m & 3][128 + i] = a2;
      }
      BAR();
    }
  } else if (w == 2 || w == 3){
    // ===== A1 / C1: GRU recurrence (gh dots + act), self-contained =====
    unsigned (*hr)[32]  = (w == 2) ? h2p : h1p;
    float    (*pr)[192] = (w == 2) ? px2 : py1;
    const int lag = (w == 2) ? 1 : 4;
    for (int j = 0; j <= NT + 4; ++j){
      const int n = j - lag;
      if (n >= 0 && n < NT){
        float rx = pr[n & 3][i];
        float zx = pr[n & 3][64 + i];
        float nx = pr[n & 3][128 + i];
        unsigned hv[32];
        load_packs(hv, hr[(n - 1) & 3]);
        float rh = 0.f, zh = 0.f, nh = 0.f;
        #pragma unroll
        for (int k2 = 0; k2 < 32; ++k2){
          unsigned hk = hv[k2];
          rh = fdot2u(hk, wa[k2], rh);
          zh = fdot2u(hk, wb[k2], zh);
          nh = fdot2u(hk, wc[k2], nh);
        }
        float r = sigmoid_f(rx + rh + b0);
        float z = sigmoid_f(zx + zh + b1);
        float nn2 = tanh_f(nx + b2 + r*(nh + b3));
        h = (1.f - z)*nn2 + z*h;
        reinterpret_cast<_Float16*>(hr[n & 3])[i] = (_Float16)h;
      }
      BAR();
    }
  } else {
    // ===== B / D: output head (Wo dots + e_func + y), B also feeds y1 packs =====
    unsigned (*hr)[32] = (w == 4) ? h2p : h1p;
    const int lag  = (w == 4) ? 2 : 5;
    const int xoff = (w == 4) ? 0 : 64;
    for (int j = 0; j <= NT + 4; ++j){
      const int m = j - lag;
      if (m >= 0 && m < NT){
        unsigned hv[32];
        load_packs(hv, hr[m & 3]);
        float s = 0.f, t = 0.f;
        #pragma unroll
        for (int k2 = 0; k2 < 32; ++k2){
          unsigned hk = hv[k2];
          s = fdot2u(hk, wa[k2], s);
          t = fdot2u(hk, wb[k2], t);
        }
        float y = e_func(s + b0) * xr0 + (t + b1);
        out[xbase + (long)m*NC + xoff + i] = y;
        if (w == 4) reinterpret_cast<_Float16*>(y1p[m & 3])[i] = (_Float16)y;
        xr0 = xr1;
        const int nn = (m + 2 < NT) ? m + 2 : NT - 1;
        xr1 = x[xbase + (long)nn*NC + xoff + i];
      }
      BAR();
    }
  }
}

extern "C" void kernel_launch(void* const* d_in, const int* in_sizes, int n_in,
                              void* d_out, int out_size, void* d_ws, size_t ws_size,
                              hipStream_t stream) {
  const float* x   = (const float*)d_in[0];
  const float* Wx1 = (const float*)d_in[1];
  const float* Wh1 = (const float*)d_in[2];
  const float* bx1 = (const float*)d_in[3];
  const float* bh1 = (const float*)d_in[4];
  const float* Wo1 = (const float*)d_in[5];
  const float* bo1 = (const float*)d_in[6];
  const float* Wx2 = (const float*)d_in[7];
  const float* Wh2 = (const float*)d_in[8];
  const float* bx2 = (const float*)d_in[9];
  const float* bh2 = (const float*)d_in[10];
  const float* Wo2 = (const float*)d_in[11];
  const float* bo2 = (const float*)d_in[12];
  float* out = (float*)d_out;

  hipLaunchKernelGGL(glow_gru_kernel, dim3(NB), dim3(384), 0, stream,
                     x, Wx1, Wh1, bx1, bh1, Wo1, bo1,
                     Wx2, Wh2, bx2, bh2, Wo2, bo2, out);
}

// Round 7
// 456.915 us; speedup vs baseline: 2.1609x; 1.6350x over previous
//
#include <hip/hip_runtime.h>

#define NB 256
#define NT 1024
#define NC 128
#define ND 64

typedef _Float16 f16x2_t __attribute__((ext_vector_type(2)));

__device__ __forceinline__ float fexp2(float x){
#if __has_builtin(__builtin_amdgcn_exp2f)
  return __builtin_amdgcn_exp2f(x);
#else
  return exp2f(x);
#endif
}
__device__ __forceinline__ float frcp_(float x){
#if __has_builtin(__builtin_amdgcn_rcpf)
  return __builtin_amdgcn_rcpf(x);
#else
  return 1.0f / x;
#endif
}
__device__ __forceinline__ float sigmoid_f(float x){
  return frcp_(1.0f + fexp2(-1.4426950408889634f * x));
}
__device__ __forceinline__ float tanh_f(float x){
  return 1.0f - 2.0f * frcp_(fexp2(2.8853900817779268f * x) + 1.0f);
}
// exp(CLAMP*0.636*atan(s/CLAMP)) with CLAMP=5 -> exp(3.18*atan(0.2*s))
__device__ __forceinline__ float e_func(float s){
  float u = 0.2f * s;
  float au = fabsf(u);
  bool inv = au > 1.0f;
  float v = inv ? frcp_(au) : au;
  float v2 = v * v;
  float pp = -0.0117212f;
  pp = pp * v2 + 0.05265332f;
  pp = pp * v2 - 0.11643287f;
  pp = pp * v2 + 0.19354346f;
  pp = pp * v2 - 0.33262347f;
  pp = pp * v2 + 0.99997726f;
  float at = pp * v;
  if (inv) at = 1.5707963267948966f - at;
  at = __builtin_copysignf(at, u);
  return fexp2(4.5877702301963f * at); // 3.18 * log2(e) * atan
}

__device__ __forceinline__ unsigned packh(float a, float b){
  union { _Float16 h[2]; unsigned u; } v;
  v.h[0] = (_Float16)a; v.h[1] = (_Float16)b;
  return v.u;
}
__device__ __forceinline__ float fdot2u(unsigned a, unsigned b, float c){
#if __has_builtin(__builtin_amdgcn_fdot2)
  return __builtin_amdgcn_fdot2(__builtin_bit_cast(f16x2_t, a), __builtin_bit_cast(f16x2_t, b), c, false);
#else
  f16x2_t av = __builtin_bit_cast(f16x2_t, a);
  f16x2_t bv = __builtin_bit_cast(f16x2_t, b);
  return c + (float)av[0]*(float)bv[0] + (float)av[1]*(float)bv[1];
#endif
}
__device__ __forceinline__ void load16(unsigned* d, const unsigned* s){
  #pragma unroll
  for (int j = 0; j < 4; ++j){
    uint4 v = reinterpret_cast<const uint4*>(s)[j];
    d[4*j+0]=v.x; d[4*j+1]=v.y; d[4*j+2]=v.z; d[4*j+3]=v.w;
  }
}
__device__ __forceinline__ void load32(unsigned* d, const unsigned* s){
  #pragma unroll
  for (int j = 0; j < 8; ++j){
    uint4 v = reinterpret_cast<const uint4*>(s)[j];
    d[4*j+0]=v.x; d[4*j+1]=v.y; d[4*j+2]=v.z; d[4*j+3]=v.w;
  }
}

// full-k dot, 2 accumulators (chain depth 16)
#define DOT32_2(res, V, W) { float aA=0.f, aB=0.f; \
  _Pragma("unroll") for (int kk=0; kk<16; ++kk){ \
    aA = fdot2u((V)[kk],    (W)[kk],    aA); \
    aB = fdot2u((V)[kk+16], (W)[kk+16], aB); } \
  res = aA + aB; }
// half-k dot
#define DOT16_1(res, V, W) { float aA=0.f; \
  _Pragma("unroll") for (int kk=0; kk<16; ++kk){ \
    aA = fdot2u((V)[kk], (W)[kk], aA); } \
  res = aA; }

// LDS-only barrier (single asm blob; no sched_barrier pins, no vmcnt drain)
#define BAR() asm volatile("s_waitcnt lgkmcnt(0)\n\ts_barrier" ::: "memory")

// 8-wave, 4-step superphase pipeline; ONE barrier per superphase.
// Roles: w0=A1(h2 rec)@4(J-1)  w1=C1(h1 rec)@4(J-4)
//        w2=A2b(gx2 hi-k)@4J   w3=C2b(gy1 hi-k)@4(J-3)
//        w4=A2a(gx2 lo-k,+x2 staging)@4J  w5=C2a(gy1 lo-k)@4(J-3)
//        w6=B(Wo2+y1)@4(J-2)   w7=D(Wo1+y2)@4(J-5)
// SIMDs: S0={A1,A2a} S1={C1,C2a} S2={A2b,B} S3={C2b,D}
__global__ __launch_bounds__(512, 1)
void glow_gru_kernel(const float* __restrict__ x,
                     const float* __restrict__ Wx1, const float* __restrict__ Wh1,
                     const float* __restrict__ bx1, const float* __restrict__ bh1,
                     const float* __restrict__ Wo1, const float* __restrict__ bo1,
                     const float* __restrict__ Wx2, const float* __restrict__ Wh2,
                     const float* __restrict__ bx2, const float* __restrict__ bh2,
                     const float* __restrict__ Wo2, const float* __restrict__ bo2,
                     float* __restrict__ out)
{
  __shared__ __align__(16) unsigned x2p[8][32];   // x2(t) f16 packs   (A2a -> A2a/A2b)
  __shared__ __align__(16) unsigned h2p[8][32];   // h2(t) packs       (A1 -> A1 self, B)
  __shared__ __align__(16) unsigned y1p[8][32];   // y1(t) packs       (B -> C2a/C2b)
  __shared__ __align__(16) unsigned h1p[8][32];   // h1(t) packs       (C1 -> C1 self, D)
  __shared__ float px2a[8][192], px2b[8][192];    // gx2 k-half partials (A2a/A2b -> A1)
  __shared__ float py1a[8][192], py1b[8][192];    // gy1 k-half partials (C2a/C2b -> C1)

  const int l = threadIdx.x;
  const int w = l >> 6;
  const int i = l & 63;
  const int b = blockIdx.x;
  const long xbase = (long)b * NT * NC;

  if (l < 32){ h2p[7][l] = 0u; h1p[7][l] = 0u; }

  unsigned wa[32], wb[32], wc[32];
  float b0=0.f, b1=0.f, b2=0.f, b3=0.f;
  float xg[4] = {0.f,0.f,0.f,0.f}, xn[4];
  float h = 0.f;

  if (w == 0){            // A1: Wh2 full-k
    #pragma unroll
    for (int k2 = 0; k2 < 32; ++k2){
      wa[k2] = packh(Wh2[(2*k2)*192 + i],       Wh2[(2*k2+1)*192 + i]);
      wb[k2] = packh(Wh2[(2*k2)*192 + 64 + i],  Wh2[(2*k2+1)*192 + 64 + i]);
      wc[k2] = packh(Wh2[(2*k2)*192 + 128 + i], Wh2[(2*k2+1)*192 + 128 + i]);
    }
    b0 = bx2[i] + bh2[i];
    b1 = bx2[64+i] + bh2[64+i];
    b2 = bx2[128+i];
    b3 = bh2[128+i];
  } else if (w == 1){     // C1: Wh1 full-k
    #pragma unroll
    for (int k2 = 0; k2 < 32; ++k2){
      wa[k2] = packh(Wh1[(2*k2)*192 + i],       Wh1[(2*k2+1)*192 + i]);
      wb[k2] = packh(Wh1[(2*k2)*192 + 64 + i],  Wh1[(2*k2+1)*192 + 64 + i]);
      wc[k2] = packh(Wh1[(2*k2)*192 + 128 + i], Wh1[(2*k2+1)*192 + 128 + i]);
    }
    b0 = bx1[i] + bh1[i];
    b1 = bx1[64+i] + bh1[64+i];
    b2 = bx1[128+i];
    b3 = bh1[128+i];
  } else if (w == 2 || w == 4){   // A2b (kh=1) / A2a (kh=0): Wx2 k-half
    const int kh = (w == 2) ? 1 : 0;
    #pragma unroll
    for (int k2 = 0; k2 < 16; ++k2){
      const int k = kh*32 + 2*k2;
      wa[k2] = packh(Wx2[k*192 + i],       Wx2[(k+1)*192 + i]);
      wb[k2] = packh(Wx2[k*192 + 64 + i],  Wx2[(k+1)*192 + 64 + i]);
      wc[k2] = packh(Wx2[k*192 + 128 + i], Wx2[(k+1)*192 + 128 + i]);
    }
    if (w == 4){
      // direct-stage x2(0..3); preload xg = x2(4..7)
      #pragma unroll
      for (int s = 0; s < 4; ++s){
        float v = x[xbase + (long)s*NC + 64 + i];
        reinterpret_cast<_Float16*>(x2p[s])[i] = (_Float16)v;
      }
      #pragma unroll
      for (int s = 0; s < 4; ++s) xg[s] = x[xbase + (long)(4+s)*NC + 64 + i];
    }
  } else if (w == 3 || w == 5){   // C2b (kh=1) / C2a (kh=0): Wx1 k-half
    const int kh = (w == 3) ? 1 : 0;
    #pragma unroll
    for (int k2 = 0; k2 < 16; ++k2){
      const int k = kh*32 + 2*k2;
      wa[k2] = packh(Wx1[k*192 + i],       Wx1[(k+1)*192 + i]);
      wb[k2] = packh(Wx1[k*192 + 64 + i],  Wx1[(k+1)*192 + 64 + i]);
      wc[k2] = packh(Wx1[k*192 + 128 + i], Wx1[(k+1)*192 + 128 + i]);
    }
  } else if (w == 6){     // B: Wo2
    #pragma unroll
    for (int k2 = 0; k2 < 32; ++k2){
      wa[k2] = packh(Wo2[(2*k2)*128 + i],      Wo2[(2*k2+1)*128 + i]);
      wb[k2] = packh(Wo2[(2*k2)*128 + 64 + i], Wo2[(2*k2+1)*128 + 64 + i]);
    }
    b0 = bo2[i]; b1 = bo2[64+i];
  } else {                // D: Wo1
    #pragma unroll
    for (int k2 = 0; k2 < 32; ++k2){
      wa[k2] = packh(Wo1[(2*k2)*128 + i],      Wo1[(2*k2+1)*128 + i]);
      wb[k2] = packh(Wo1[(2*k2)*128 + 64 + i], Wo1[(2*k2+1)*128 + 64 + i]);
    }
    b0 = bo1[i]; b1 = bo1[64+i];
  }
  __syncthreads();

  for (int J = 0; J <= 260; ++J){
    if (w == 0 || w == 1){
      // ===== A1 / C1: GRU recurrence, 4 serial steps =====
      unsigned (*hr)[32]  = (w == 0) ? h2p : h1p;
      float    (*pa)[192] = (w == 0) ? px2a : py1a;
      float    (*pb)[192] = (w == 0) ? px2b : py1b;
      const int t0 = (w == 0) ? 4*(J-1) : 4*(J-4);
      if (t0 >= 0 && t0 < NT){
        #pragma unroll
        for (int s = 0; s < 4; ++s){
          const int t = t0 + s;
          float rxa = pa[t&7][i],      rxb = pb[t&7][i];
          float zxa = pa[t&7][64+i],   zxb = pb[t&7][64+i];
          float nxa = pa[t&7][128+i],  nxb = pb[t&7][128+i];
          unsigned hv[32];
          load32(hv, hr[(t-1) & 7]);
          float rh, zh, nh;
          DOT32_2(rh, hv, wa);
          DOT32_2(zh, hv, wb);
          DOT32_2(nh, hv, wc);
          float r = sigmoid_f(rxa + rxb + rh + b0);
          float z = sigmoid_f(zxa + zxb + zh + b1);
          float nn = tanh_f(nxa + nxb + b2 + r*(nh + b3));
          h = (1.f - z)*nn + z*h;
          reinterpret_cast<_Float16*>(hr[t&7])[i] = (_Float16)h;
        }
      }
    } else if (w == 2 || w == 4 || w == 3 || w == 5){
      // ===== A2a/A2b / C2a/C2b: feed-forward gate k-half matvecs =====
      const bool isA = (w == 2 || w == 4);
      const int kh = (w == 2 || w == 3) ? 1 : 0;
      unsigned (*src)[32] = isA ? x2p : y1p;
      float (*dst)[192] = isA ? ((kh == 0) ? px2a : px2b)
                              : ((kh == 0) ? py1a : py1b);
      const int t0 = isA ? 4*J : 4*(J-3);
      if (w == 4){
        // prefetch x2 for super J+2 (consumed as staging at J+1)
        const int tl0 = 4*(J+2);
        #pragma unroll
        for (int s = 0; s < 4; ++s){
          const int tt = tl0 + s;
          xn[s] = (tt < NT) ? x[xbase + (long)tt*NC + 64 + i] : 0.f;
        }
      }
      if (t0 >= 0 && t0 < NT){
        #pragma unroll
        for (int s = 0; s < 4; ++s){
          const int t = t0 + s;
          unsigned hv[16];
          load16(hv, src[t&7] + kh*16);
          float a0, a1, a2;
          DOT16_1(a0, hv, wa);
          DOT16_1(a1, hv, wb);
          DOT16_1(a2, hv, wc);
          dst[t&7][i] = a0; dst[t&7][64+i] = a1; dst[t&7][128+i] = a2;
        }
      }
      if (w == 4){
        // stage x2 packs for super J+1's steps
        const int tn0 = 4*(J+1);
        if (tn0 < NT){
          #pragma unroll
          for (int s = 0; s < 4; ++s)
            reinterpret_cast<_Float16*>(x2p[(tn0+s)&7])[i] = (_Float16)xg[s];
        }
        #pragma unroll
        for (int s = 0; s < 4; ++s) xg[s] = xn[s];
      }
    } else {
      // ===== B / D: output heads =====
      const bool isB = (w == 6);
      unsigned (*hr)[32] = isB ? h2p : h1p;
      const int t0  = isB ? 4*(J-2) : 4*(J-5);
      const int tl0 = isB ? 4*(J-1) : 4*(J-4);
      const int xoff = isB ? 0 : 64;
      #pragma unroll
      for (int s = 0; s < 4; ++s){
        const int tt = tl0 + s;
        xn[s] = (tt >= 0 && tt < NT) ? x[xbase + (long)tt*NC + xoff + i] : 0.f;
      }
      if (t0 >= 0 && t0 < NT){
        #pragma unroll
        for (int s = 0; s < 4; ++s){
          const int t = t0 + s;
          unsigned hv[32];
          load32(hv, hr[t&7]);
          float sv, tv;
          DOT32_2(sv, hv, wa);
          DOT32_2(tv, hv, wb);
          float y = e_func(sv + b0) * xg[s] + (tv + b1);
          out[xbase + (long)t*NC + xoff + i] = y;
          if (isB) reinterpret_cast<_Float16*>(y1p[t&7])[i] = (_Float16)y;
        }
      }
      #pragma unroll
      for (int s = 0; s < 4; ++s) xg[s] = xn[s];
    }
    BAR();
  }
}

extern "C" void kernel_launch(void* const* d_in, const int* in_sizes, int n_in,
                              void* d_out, int out_size, void* d_ws, size_t ws_size,
                              hipStream_t stream) {
  const float* x   = (const float*)d_in[0];
  const float* Wx1 = (const float*)d_in[1];
  const float* Wh1 = (const float*)d_in[2];
  const float* bx1 = (const float*)d_in[3];
  const float* bh1 = (const float*)d_in[4];
  const float* Wo1 = (const float*)d_in[5];
  const float* bo1 = (const float*)d_in[6];
  const float* Wx2 = (const float*)d_in[7];
  const float* Wh2 = (const float*)d_in[8];
  const float* bx2 = (const float*)d_in[9];
  const float* bh2 = (const float*)d_in[10];
  const float* Wo2 = (const float*)d_in[11];
  const float* bo2 = (const float*)d_in[12];
  float* out = (float*)d_out;

  hipLaunchKernelGGL(glow_gru_kernel, dim3(NB), dim3(512), 0, stream,
                     x, Wx1, Wh1, bx1, bh1, Wo1, bo1,
                     Wx2, Wh2, bx2, bh2, Wo2, bo2, out);
}

// Round 8
// 440.786 us; speedup vs baseline: 2.2399x; 1.0366x over previous
//
#include <hip/hip_runtime.h>

#define NB 256
#define NT 1024
#define NC 128
#define ND 64

typedef _Float16 f16x8 __attribute__((ext_vector_type(8)));
typedef float f32x4 __attribute__((ext_vector_type(4)));

__device__ __forceinline__ float fexp2(float x){
#if __has_builtin(__builtin_amdgcn_exp2f)
  return __builtin_amdgcn_exp2f(x);
#else
  return exp2f(x);
#endif
}
__device__ __forceinline__ float frcp_(float x){
#if __has_builtin(__builtin_amdgcn_rcpf)
  return __builtin_amdgcn_rcpf(x);
#else
  return 1.0f / x;
#endif
}
__device__ __forceinline__ float sigmoid_f(float x){
  return frcp_(1.0f + fexp2(-1.4426950408889634f * x));
}
__device__ __forceinline__ float tanh_f(float x){
  return 1.0f - 2.0f * frcp_(fexp2(2.8853900817779268f * x) + 1.0f);
}
// exp(CLAMP*0.636*atan(s/CLAMP)) with CLAMP=5 -> exp(3.18*atan(0.2*s))
__device__ __forceinline__ float e_func(float s){
  float u = 0.2f * s;
  float au = fabsf(u);
  bool inv = au > 1.0f;
  float v = inv ? frcp_(au) : au;
  float v2 = v * v;
  float pp = -0.0117212f;
  pp = pp * v2 + 0.05265332f;
  pp = pp * v2 - 0.11643287f;
  pp = pp * v2 + 0.19354346f;
  pp = pp * v2 - 0.33262347f;
  pp = pp * v2 + 0.99997726f;
  float at = pp * v;
  if (inv) at = 1.5707963267948966f - at;
  at = __builtin_copysignf(at, u);
  return fexp2(4.5877702301963f * at); // 3.18 * log2(e) * atan
}

// LDS-only barrier (single asm blob; no sched_barrier pins, no vmcnt drain)
#define BAR() asm volatile("s_waitcnt lgkmcnt(0)\n\ts_barrier" ::: "memory")

// A-fragment for mfma_f32_16x16x32_f16 with row-replicated A (A[r][k]=v[k]):
// lane l needs v[8*(l>>4)+j + 32*ks], j=0..7 -> one b128 broadcast read.
__device__ __forceinline__ f16x8 ldaf(const _Float16* pack, int lane, int ks){
  return *reinterpret_cast<const f16x8*>(
      reinterpret_cast<const char*>(pack) + 16*(lane>>4) + 64*ks);
}
// B-fragment: lane l holds B[k=32*ks+8*(l>>4)+j][c=tile*16+(l&15)]
__device__ __forceinline__ f16x8 bld(const float* __restrict__ W, int ldw,
                                     int ks, int tile, int lane){
  f16x8 v;
  const int kb = ks*32 + 8*(lane>>4);
  const int c  = tile*16 + (lane&15);
  #pragma unroll
  for (int j = 0; j < 8; ++j) v[j] = (_Float16)W[(kb + j)*ldw + c];
  return v;
}
// C/D: col=lane&15, rows replicated -> lane picks tile (lane>>4) via 2-level select
__device__ __forceinline__ float sel4(float a0, float a1, float a2, float a3, int lane){
  float t01 = (lane & 16) ? a1 : a0;
  float t23 = (lane & 16) ? a3 : a2;
  return (lane & 32) ? t23 : t01;
}
#define MFMA16(acc, a, bfr) acc = __builtin_amdgcn_mfma_f32_16x16x32_f16(a, bfr, acc, 0, 0, 0)

// 6-wave superphase pipeline (4 steps / barrier), matvecs on the MFMA pipe.
// Waves: w0=A2(gx2)@4J  w1=C2(gy1)@4(J-3)  w2=A1(h2 rec)@4(J-1)
//        w3=C1(h1 rec)@4(J-4)  w4=B(Wo2+y1)@4(J-2)  w5=D(Wo1+y2)@4(J-5)
// SIMDs: S0={A2,B} S1={C2,D} S2={A1} S3={C1}
__global__ __launch_bounds__(384, 1)
void glow_gru_kernel(const float* __restrict__ x,
                     const float* __restrict__ Wx1, const float* __restrict__ Wh1,
                     const float* __restrict__ bx1, const float* __restrict__ bh1,
                     const float* __restrict__ Wo1, const float* __restrict__ bo1,
                     const float* __restrict__ Wx2, const float* __restrict__ Wh2,
                     const float* __restrict__ bx2, const float* __restrict__ bh2,
                     const float* __restrict__ Wo2, const float* __restrict__ bo2,
                     float* __restrict__ out)
{
  __shared__ __align__(16) _Float16 x2p[8][64];   // x2(t) packs   (A2 self, staged 1 super ahead)
  __shared__ __align__(16) _Float16 h2p[8][64];   // h2(t) packs   (A1 -> A1 self, B)
  __shared__ __align__(16) _Float16 y1p[8][64];   // y1(t) packs   (B -> C2)
  __shared__ __align__(16) _Float16 h1p[8][64];   // h1(t) packs   (C1 -> C1 self, D)
  __shared__ float px2[8][192];                   // gx2 partials  (A2 -> A1)
  __shared__ float py1[8][192];                   // gy1 partials  (C2 -> C1)

  const int l = threadIdx.x;
  const int w = l >> 6;
  const int i = l & 63;
  const int b = blockIdx.x;
  const long xbase = (long)b * NT * NC;

  if (l < 64){ h2p[7][l] = (_Float16)0.f; h1p[7][l] = (_Float16)0.f; }

  if (w == 0){
    // ================= A2: gx2 = Wx2^T x2 =================
    f16x8 bf[12][2];
    #pragma unroll
    for (int t = 0; t < 12; ++t){ bf[t][0] = bld(Wx2,192,0,t,i); bf[t][1] = bld(Wx2,192,1,t,i); }
    float xg[4], xn[4];
    #pragma unroll
    for (int s = 0; s < 4; ++s){
      x2p[s][i] = (_Float16)x[xbase + (long)s*NC + 64 + i];
      xg[s] = x[xbase + (long)(4+s)*NC + 64 + i];
    }
    __syncthreads();
    for (int J = 0; J <= 260; ++J){
      const int t0 = 4*J;
      #pragma unroll
      for (int s = 0; s < 4; ++s){
        const int tt = 4*(J+2) + s;
        xn[s] = (tt < NT) ? x[xbase + (long)tt*NC + 64 + i] : 0.f;
      }
      if (t0 < NT){
        f16x8 af[4][2];
        #pragma unroll
        for (int s = 0; s < 4; ++s){
          af[s][0] = ldaf(x2p[(t0+s)&7], i, 0);
          af[s][1] = ldaf(x2p[(t0+s)&7], i, 1);
        }
        #pragma unroll
        for (int s = 0; s < 4; ++s){
          f32x4 acc[12];
          #pragma unroll
          for (int t2 = 0; t2 < 12; ++t2){
            acc[t2] = (f32x4)0.f;
            MFMA16(acc[t2], af[s][0], bf[t2][0]);
            MFMA16(acc[t2], af[s][1], bf[t2][1]);
          }
          if (i < 16){
            #pragma unroll
            for (int t2 = 0; t2 < 12; ++t2) px2[(t0+s)&7][t2*16 + i] = acc[t2][0];
          }
        }
        const int tn0 = 4*(J+1);
        if (tn0 < NT){
          #pragma unroll
          for (int s = 0; s < 4; ++s) x2p[(tn0+s)&7][i] = (_Float16)xg[s];
        }
        #pragma unroll
        for (int s = 0; s < 4; ++s) xg[s] = xn[s];
      }
      BAR();
    }
  } else if (w == 1){
    // ================= C2: gy1 = Wx1^T y1 =================
    f16x8 bf[12][2];
    #pragma unroll
    for (int t = 0; t < 12; ++t){ bf[t][0] = bld(Wx1,192,0,t,i); bf[t][1] = bld(Wx1,192,1,t,i); }
    __syncthreads();
    for (int J = 0; J <= 260; ++J){
      const int t0 = 4*(J-3);
      if (t0 >= 0 && t0 < NT){
        f16x8 af[4][2];
        #pragma unroll
        for (int s = 0; s < 4; ++s){
          af[s][0] = ldaf(y1p[(t0+s)&7], i, 0);
          af[s][1] = ldaf(y1p[(t0+s)&7], i, 1);
        }
        #pragma unroll
        for (int s = 0; s < 4; ++s){
          f32x4 acc[12];
          #pragma unroll
          for (int t2 = 0; t2 < 12; ++t2){
            acc[t2] = (f32x4)0.f;
            MFMA16(acc[t2], af[s][0], bf[t2][0]);
            MFMA16(acc[t2], af[s][1], bf[t2][1]);
          }
          if (i < 16){
            #pragma unroll
            for (int t2 = 0; t2 < 12; ++t2) py1[(t0+s)&7][t2*16 + i] = acc[t2][0];
          }
        }
      }
      BAR();
    }
  } else if (w == 2 || w == 3){
    // ================= A1 / C1: GRU recurrence =================
    const bool isA = (w == 2);
    const float* WH = isA ? Wh2 : Wh1;
    const float* bx = isA ? bx2 : bx1;
    const float* bh = isA ? bh2 : bh1;
    _Float16 (*hr)[64] = isA ? h2p : h1p;
    float (*pr)[192]   = isA ? px2 : py1;
    const int lag = isA ? 1 : 4;
    f16x8 bf[12][2];
    #pragma unroll
    for (int t = 0; t < 12; ++t){ bf[t][0] = bld(WH,192,0,t,i); bf[t][1] = bld(WH,192,1,t,i); }
    const float b0 = bx[i] + bh[i];
    const float b1 = bx[64+i] + bh[64+i];
    const float b2v = bx[128+i], b3v = bh[128+i];
    float h = 0.f;
    __syncthreads();
    for (int J = 0; J <= 260; ++J){
      const int t0 = 4*(J - lag);
      if (t0 >= 0 && t0 < NT){
        float rxs[4], zxs[4], nxs[4];
        #pragma unroll
        for (int s = 0; s < 4; ++s){
          rxs[s] = pr[(t0+s)&7][i];
          zxs[s] = pr[(t0+s)&7][64+i];
          nxs[s] = pr[(t0+s)&7][128+i];
        }
        #pragma unroll
        for (int s = 0; s < 4; ++s){
          const int t = t0 + s;
          f16x8 a0 = ldaf(hr[(t-1)&7], i, 0);
          f16x8 a1 = ldaf(hr[(t-1)&7], i, 1);
          f32x4 acc[12];
          #pragma unroll
          for (int t2 = 0; t2 < 12; ++t2){
            acc[t2] = (f32x4)0.f;
            MFMA16(acc[t2], a0, bf[t2][0]);
            MFMA16(acc[t2], a1, bf[t2][1]);
          }
          float rh = sel4(acc[0][0], acc[1][0], acc[2][0],  acc[3][0],  i);
          float zh = sel4(acc[4][0], acc[5][0], acc[6][0],  acc[7][0],  i);
          float nh = sel4(acc[8][0], acc[9][0], acc[10][0], acc[11][0], i);
          float r = sigmoid_f(rxs[s] + rh + b0);
          float z = sigmoid_f(zxs[s] + zh + b1);
          float nn = tanh_f(nxs[s] + b2v + r*(nh + b3v));
          h = (1.f - z)*nn + z*h;
          hr[t&7][i] = (_Float16)h;
        }
      }
      BAR();
    }
  } else {
    // ================= B / D: output heads =================
    const bool isB = (w == 4);
    const float* WO = isB ? Wo2 : Wo1;
    const float* bo = isB ? bo2 : bo1;
    _Float16 (*hr)[64] = isB ? h2p : h1p;
    const int lag  = isB ? 2 : 5;
    const int xoff = isB ? 0 : 64;
    f16x8 bf[8][2];
    #pragma unroll
    for (int t = 0; t < 8; ++t){ bf[t][0] = bld(WO,128,0,t,i); bf[t][1] = bld(WO,128,1,t,i); }
    const float b0 = bo[i], b1 = bo[64+i];
    float xg[4], xn[4];
    #pragma unroll
    for (int s = 0; s < 4; ++s) xg[s] = x[xbase + (long)s*NC + xoff + i];
    __syncthreads();
    for (int J = 0; J <= 260; ++J){
      const int t0 = 4*(J - lag);
      #pragma unroll
      for (int s = 0; s < 4; ++s){
        const int tt = 4*(J - lag + 1) + s;
        xn[s] = (tt >= 0 && tt < NT) ? x[xbase + (long)tt*NC + xoff + i] : 0.f;
      }
      if (t0 >= 0 && t0 < NT){
        f16x8 af[4][2];
        #pragma unroll
        for (int s = 0; s < 4; ++s){
          af[s][0] = ldaf(hr[(t0+s)&7], i, 0);
          af[s][1] = ldaf(hr[(t0+s)&7], i, 1);
        }
        #pragma unroll
        for (int s = 0; s < 4; ++s){
          const int t = t0 + s;
          f32x4 acc[8];
          #pragma unroll
          for (int t2 = 0; t2 < 8; ++t2){
            acc[t2] = (f32x4)0.f;
            MFMA16(acc[t2], af[s][0], bf[t2][0]);
            MFMA16(acc[t2], af[s][1], bf[t2][1]);
          }
          float sv = sel4(acc[0][0], acc[1][0], acc[2][0], acc[3][0], i);
          float tv = sel4(acc[4][0], acc[5][0], acc[6][0], acc[7][0], i);
          float y = e_func(sv + b0) * xg[s] + (tv + b1);
          out[xbase + (long)t*NC + xoff + i] = y;
          if (isB) y1p[t&7][i] = (_Float16)y;
        }
        #pragma unroll
        for (int s = 0; s < 4; ++s) xg[s] = xn[s];
      }
      BAR();
    }
  }
}

extern "C" void kernel_launch(void* const* d_in, const int* in_sizes, int n_in,
                              void* d_out, int out_size, void* d_ws, size_t ws_size,
                              hipStream_t stream) {
  const float* x   = (const float*)d_in[0];
  const float* Wx1 = (const float*)d_in[1];
  const float* Wh1 = (const float*)d_in[2];
  const float* bx1 = (const float*)d_in[3];
  const float* bh1 = (const float*)d_in[4];
  const float* Wo1 = (const float*)d_in[5];
  const float* bo1 = (const float*)d_in[6];
  const float* Wx2 = (const float*)d_in[7];
  const float* Wh2 = (const float*)d_in[8];
  const float* bx2 = (const float*)d_in[9];
  const float* bh2 = (const float*)d_in[10];
  const float* Wo2 = (const float*)d_in[11];
  const float* bo2 = (const float*)d_in[12];
  float* out = (float*)d_out;

  hipLaunchKernelGGL(glow_gru_kernel, dim3(NB), dim3(384), 0, stream,
                     x, Wx1, Wh1, bx1, bh1, Wo1, bo1,
                     Wx2, Wh2, bx2, bh2, Wo2, bo2, out);
}